// Round 4
// baseline (128.420 us; speedup 1.0000x reference)
//
#include <hip/hip_runtime.h>
#include <math.h>

// ---------------------------------------------------------------------------
// mLSTM cell, MFMA bf16. Round 4: k_attn reads K/V fragments DIRECTLY from
// global (L2-resident per-XCD), only W goes through LDS (4KB). 512 blocks
// (32-row q-tiles) -> 2 blocks/CU co-resident; balanced depth pairing.
// Identities: a[t]=ig[t]-cs[t], m[s]=prefix-max a, D=exp(a[t]-m[s]),
//   floor[s]=exp(-(cs[s]+m[s])); row work additive in t.
// ---------------------------------------------------------------------------

#define BB   2
#define SS   2048
#define DD   1024
#define NHH  4
#define DHH  256
#define BHH  (BB*NHH)

// Workspace byte offsets (total ~32.5 MB)
#define QB_OFF   ((size_t)0)
#define KB_OFF   ((size_t)8  << 20)
#define VT_OFF   ((size_t)16 << 20)
#define VB_OFF   ((size_t)24 << 20)
#define IG_OFF   ((size_t)32 << 20)
#define LSF_OFF  (IG_OFF  + ((size_t)64<<10))
#define AA_OFF   (LSF_OFF + ((size_t)64<<10))
#define MM_OFF   (AA_OFF  + ((size_t)64<<10))
#define FLR_OFF  (MM_OFF  + ((size_t)64<<10))
#define WSI_OFF  (FLR_OFF + ((size_t)64<<10))
#define WSF_OFF  (WSI_OFF + ((size_t)32<<10))

typedef __attribute__((ext_vector_type(8))) short short8;   // 8 bf16 (4 VGPR)
typedef __attribute__((ext_vector_type(4))) float f32x4;

__device__ __forceinline__ unsigned short f2b(float f) {
  union { float f; unsigned int u; } v; v.f = f;
  unsigned int r = (v.u + 0x7FFFu + ((v.u >> 16) & 1u)) >> 16;
  return (unsigned short)r;
}

// ---------------------------------------------------------------------------
// Kernel 0: gate weight pre-sum: wsum[n][c] = sum of 3 D-segments.
// ---------------------------------------------------------------------------
__global__ __launch_bounds__(256) void k_gw(
    const float* __restrict__ wi, const float* __restrict__ wf,
    float* __restrict__ wsi, float* __restrict__ wsf)
{
  const int idx = blockIdx.x*256 + threadIdx.x;   // 0..8191
  const int n = idx >> 10, c = idx & 1023;
  wsi[idx] = wi[n*3*DD + c] + wi[n*3*DD + DD + c] + wi[n*3*DD + 2*DD + c];
  wsf[idx] = wf[n*3*DD + c] + wf[n*3*DD + DD + c] + wf[n*3*DD + 2*DD + c];
}

// ---------------------------------------------------------------------------
// Kernel 1: headwise QKV projection (4x4 blocks) + gate GEMVs. bf16 outputs.
// ---------------------------------------------------------------------------
__global__ __launch_bounds__(256) void k_proj(
    const float* __restrict__ x,
    const float* __restrict__ wq, const float* __restrict__ wk, const float* __restrict__ wv,
    const float* __restrict__ wsi, const float* __restrict__ bi,
    const float* __restrict__ wsf, const float* __restrict__ bf,
    unsigned short* __restrict__ qb, unsigned short* __restrict__ kb,
    unsigned short* __restrict__ vb, float* __restrict__ ig, float* __restrict__ lsf)
{
  const int row = blockIdx.x;          // b*SS + s
  const int b   = row >> 11;
  const int s   = row & (SS-1);
  const int g   = threadIdx.x;         // qkv head 0..255

  const float4 xv = *(const float4*)(x + (size_t)row*DD + (g<<2));

  const int h   = g >> 6;
  const int dh0 = (g & 63) << 2;
  const size_t qi = ((size_t)(b*NHH + h)*SS + s)*DHH + dh0;

  {
    const float4 w0 = *(const float4*)(wq + g*16 + 0);
    const float4 w1 = *(const float4*)(wq + g*16 + 4);
    const float4 w2 = *(const float4*)(wq + g*16 + 8);
    const float4 w3 = *(const float4*)(wq + g*16 + 12);
    ushort4 r;
    r.x = f2b(w0.x*xv.x + w0.y*xv.y + w0.z*xv.z + w0.w*xv.w);
    r.y = f2b(w1.x*xv.x + w1.y*xv.y + w1.z*xv.z + w1.w*xv.w);
    r.z = f2b(w2.x*xv.x + w2.y*xv.y + w2.z*xv.z + w2.w*xv.w);
    r.w = f2b(w3.x*xv.x + w3.y*xv.y + w3.z*xv.z + w3.w*xv.w);
    *(ushort4*)(qb + qi) = r;
  }
  {
    const float4 w0 = *(const float4*)(wk + g*16 + 0);
    const float4 w1 = *(const float4*)(wk + g*16 + 4);
    const float4 w2 = *(const float4*)(wk + g*16 + 8);
    const float4 w3 = *(const float4*)(wk + g*16 + 12);
    ushort4 r;
    r.x = f2b(0.0625f*(w0.x*xv.x + w0.y*xv.y + w0.z*xv.z + w0.w*xv.w));
    r.y = f2b(0.0625f*(w1.x*xv.x + w1.y*xv.y + w1.z*xv.z + w1.w*xv.w));
    r.z = f2b(0.0625f*(w2.x*xv.x + w2.y*xv.y + w2.z*xv.z + w2.w*xv.w));
    r.w = f2b(0.0625f*(w3.x*xv.x + w3.y*xv.y + w3.z*xv.z + w3.w*xv.w));
    *(ushort4*)(kb + qi) = r;
  }
  {
    const float4 w0 = *(const float4*)(wv + g*16 + 0);
    const float4 w1 = *(const float4*)(wv + g*16 + 4);
    const float4 w2 = *(const float4*)(wv + g*16 + 8);
    const float4 w3 = *(const float4*)(wv + g*16 + 12);
    ushort4 r;
    r.x = f2b(w0.x*xv.x + w0.y*xv.y + w0.z*xv.z + w0.w*xv.w);
    r.y = f2b(w1.x*xv.x + w1.y*xv.y + w1.z*xv.z + w1.w*xv.w);
    r.z = f2b(w2.x*xv.x + w2.y*xv.y + w2.z*xv.z + w2.w*xv.w);
    r.w = f2b(w3.x*xv.x + w3.y*xv.y + w3.z*xv.z + w3.w*xv.w);
    *(ushort4*)(vb + qi) = r;
  }

  float pi[4], pf[4];
  const int c = g << 2;
  #pragma unroll
  for (int n=0;n<4;n++) {
    const float4 a0 = *(const float4*)(wsi + n*DD + c);
    pi[n] = a0.x*xv.x + a0.y*xv.y + a0.z*xv.z + a0.w*xv.w;
    const float4 b0 = *(const float4*)(wsf + n*DD + c);
    pf[n] = b0.x*xv.x + b0.y*xv.y + b0.z*xv.z + b0.w*xv.w;
  }
  #pragma unroll
  for (int off=32; off>0; off>>=1) {
    #pragma unroll
    for (int n=0;n<4;n++) {
      pi[n] += __shfl_down(pi[n], off);
      pf[n] += __shfl_down(pf[n], off);
    }
  }
  __shared__ float red[4][8];
  const int lane = g & 63, wid = g >> 6;
  if (lane == 0) {
    #pragma unroll
    for (int n=0;n<4;n++) { red[wid][n] = pi[n]; red[wid][4+n] = pf[n]; }
  }
  __syncthreads();
  if (g < 4) {
    const int n = g;
    float ti = red[0][n]+red[1][n]+red[2][n]+red[3][n] + bi[n];
    float tf = red[0][4+n]+red[1][4+n]+red[2][4+n]+red[3][4+n] + bf[n];
    ig[(size_t)(b*NHH+n)*SS + s] = ti;
    float ls = (tf >= 0.f) ? -log1pf(expf(-tf)) : (tf - log1pf(expf(tf)));
    lsf[(size_t)(b*NHH+n)*SS + s] = ls;
  }
}

// ---------------------------------------------------------------------------
// Kernel 2: per-(b,head) scan.
// ---------------------------------------------------------------------------
__global__ __launch_bounds__(256) void k_scan(
    const float* __restrict__ ig, const float* __restrict__ lsf,
    float* __restrict__ aa, float* __restrict__ mm, float* __restrict__ flr)
{
  const int bh = blockIdx.x;
  const int tid = threadIdx.x;
  const float* igp = ig + (size_t)bh*SS;
  const float* lsp = lsf + (size_t)bh*SS;
  float* ap = aa + (size_t)bh*SS;
  float* mp = mm + (size_t)bh*SS;
  float* fp = flr + (size_t)bh*SS;

  __shared__ float sb[256];
  const int base = tid*8;
  float l[8], c[8];
  #pragma unroll
  for (int j=0;j<8;j++) l[j] = lsp[base+j];
  c[0] = l[0];
  #pragma unroll
  for (int j=1;j<8;j++) c[j] = c[j-1] + l[j];

  sb[tid] = c[7];
  __syncthreads();
  for (int off=1; off<256; off<<=1) {
    float v = sb[tid];
    float u = (tid>=off) ? sb[tid-off] : 0.f;
    __syncthreads();
    sb[tid] = v + u;
    __syncthreads();
  }
  const float exs = (tid==0) ? 0.f : sb[tid-1];

  float cs[8], a8[8], mx[8];
  #pragma unroll
  for (int j=0;j<8;j++) { cs[j] = exs + c[j]; a8[j] = igp[base+j] - cs[j]; }
  mx[0] = a8[0];
  #pragma unroll
  for (int j=1;j<8;j++) mx[j] = fmaxf(mx[j-1], a8[j]);

  __syncthreads();
  sb[tid] = mx[7];
  __syncthreads();
  for (int off=1; off<256; off<<=1) {
    float v = sb[tid];
    float u = (tid>=off) ? sb[tid-off] : -INFINITY;
    __syncthreads();
    sb[tid] = fmaxf(v, u);
    __syncthreads();
  }
  const float exm = (tid==0) ? -INFINITY : sb[tid-1];

  #pragma unroll
  for (int j=0;j<8;j++) {
    float mmx = fmaxf(exm, mx[j]);
    ap[base+j] = a8[j];
    mp[base+j] = mmx;
    fp[base+j] = expf(-(cs[j] + mmx));
  }
}

// ---------------------------------------------------------------------------
// Kernel 3: transpose V bf16 [bh][s][d] -> Vt [bh][d][s].
// ---------------------------------------------------------------------------
__global__ __launch_bounds__(256) void k_vt(
    const unsigned short* __restrict__ vb, unsigned short* __restrict__ vt)
{
  __shared__ unsigned short tile[64][72];
  const int bh = blockIdx.x, st = blockIdx.y, dt = blockIdx.z;
  const int s0 = st*64, d0 = dt*64;
  const unsigned short* src = vb + ((size_t)bh*SS + s0)*DHH + d0;
  #pragma unroll
  for (int j=0;j<2;j++){
    int f = threadIdx.x + j*256;           // 0..511
    int r = f>>3, c = (f&7)*8;
    *(uint4*)&tile[r][c] = *(const uint4*)(src + (size_t)r*DHH + c);
  }
  __syncthreads();
  unsigned short* dst = vt + ((size_t)bh*DHH + d0)*SS + s0;
  #pragma unroll
  for (int j=0;j<2;j++){
    int f = threadIdx.x + j*256;
    int dr = f>>3, sc = (f&7)*8;
    unsigned short tmp[8];
    #pragma unroll
    for (int i=0;i<8;i++) tmp[i] = tile[sc+i][dr];
    *(uint4*)(dst + (size_t)dr*SS + sc) = *(uint4*)tmp;
  }
}

// ---------------------------------------------------------------------------
// Kernel 4: MFMA attention, direct-global K/V fragments, W via 4KB LDS.
// 512 blocks = 8 bh (XCD-pinned via bid&7) x 64 q-tiles of 32 rows.
// Depth-balanced remap: CU gets dispatch pair (j, j+32); rt = 2j (j<32) /
// 127-2j (j>=32) makes depth(j)+depth(j+32) == 33 for all pairs.
// 4 waves: wave w owns QKT 16-col strip [16w,16w+16) and PV d-slice
// [64w, 64w+64). Q register-resident (64 VGPR). 2 barriers per k-tile.
// ---------------------------------------------------------------------------
__global__ __launch_bounds__(256, 2) void k_attn(
    const unsigned short* __restrict__ qb, const unsigned short* __restrict__ kb,
    const unsigned short* __restrict__ vt,
    const float* __restrict__ ab, const float* __restrict__ mb,
    const float* __restrict__ flr, const float* __restrict__ ln_w,
    float* __restrict__ out)
{
  __shared__ __align__(16) char smWb[32*128];   // W: 32 rows x 128B, swizzled
  __shared__ float smRed[32*4];
  __shared__ float smS1[32*4];
  __shared__ float smS2[32*4];

  const int bid = blockIdx.x;
  const int bh  = bid & 7;                 // XCD pin
  const int j   = bid >> 3;                // 0..63
  const int rt  = (j < 32) ? (2*j) : (127 - 2*j);
  const int s0  = rt * 32;
  const int nkt = (32*rt + 95) >> 6;       // ceil((s0+32)/64)

  const int tid  = threadIdx.x;
  const int lane = tid & 63;
  const int w    = tid >> 6;               // wave 0..3
  const int l15  = lane & 15, lg = lane >> 4;
  const int bhoff = bh * SS;
  const int b = bh >> 2, h = bh & 3;

  const char* kbh = (const char*)(kb + (size_t)bh*SS*DHH);   // rows of 512B
  const char* vth = (const char*)(vt + (size_t)bh*DHH*SS);   // d-rows of 4096B

  // Q register-resident: 32 rows (mt bands of 16)
  short8 qf[2][8];
  {
    const unsigned short* qp = qb + ((size_t)bh*SS + s0)*DHH;
    #pragma unroll
    for (int mt=0; mt<2; ++mt)
      #pragma unroll
      for (int ks=0; ks<8; ++ks)
        qf[mt][ks] = *(const short8*)(qp + (16*mt + l15)*DHH + 32*ks + 8*lg);
  }
  float mrow[2][4];
  #pragma unroll
  for (int mt=0; mt<2; ++mt)
    #pragma unroll
    for (int rr=0; rr<4; ++rr)
      mrow[mt][rr] = mb[bhoff + s0 + 16*mt + 4*lg + rr];

  f32x4 oacc[2][4];
  #pragma unroll
  for (int mt=0; mt<2; ++mt)
    #pragma unroll
    for (int nt=0; nt<4; ++nt)
      oacc[mt][nt] = (f32x4){0.f,0.f,0.f,0.f};
  float denp[2][4] = {{0.f,0.f,0.f,0.f},{0.f,0.f,0.f,0.f}};

  const int trel = 16*w + l15;             // QKT col within k-tile, 0..63

  for (int kt = 0; kt < nkt; ++kt) {
    const int t0 = kt*64;

    // ---- QK^T (K pre-scaled by 1/16): wave computes 32 rows x 16 cols ----
    f32x4 sacc[2];
    sacc[0] = (f32x4){0.f,0.f,0.f,0.f};
    sacc[1] = (f32x4){0.f,0.f,0.f,0.f};
    {
      const char* kp = kbh + (size_t)(t0 + trel)*512 + lg*16;
      #pragma unroll
      for (int ks=0; ks<8; ++ks) {
        short8 kf = *(const short8*)(kp + ks*64);
        sacc[0] = __builtin_amdgcn_mfma_f32_16x16x32_bf16(qf[0][ks], kf, sacc[0], 0, 0, 0);
        sacc[1] = __builtin_amdgcn_mfma_f32_16x16x32_bf16(qf[1][ks], kf, sacc[1], 0, 0, 0);
      }
    }

    // ---- weights: w = mask * qk * exp(a[t]-m[s]); bf16 into swizzled LDS ----
    const float av = ab[bhoff + t0 + trel];
    const bool last = (kt == nkt-1);
    #pragma unroll
    for (int mt=0; mt<2; ++mt) {
      #pragma unroll
      for (int rr=0; rr<4; ++rr) {
        const int srel = 16*mt + 4*lg + rr;
        float wv = sacc[mt][rr] * __expf(av - mrow[mt][rr]);
        if (last && (t0 + trel > s0 + srel)) wv = 0.f;
        denp[mt][rr] += wv;
        *(unsigned short*)(smWb + (size_t)srel*128 + (((trel >> 3) ^ (srel & 7))<<4)
                            + ((trel & 7)<<1)) = f2b(wv);
      }
    }
    __syncthreads();   // W visible to all waves

    // ---- PV: oacc += W @ V ; wave: 32 rows x 64-d slice ----
    #pragma unroll
    for (int kst=0; kst<2; ++kst) {
      short8 wf[2];
      #pragma unroll
      for (int mt=0; mt<2; ++mt) {
        const int sr = 16*mt + l15;
        wf[mt] = *(const short8*)(smWb + (size_t)sr*128 + (((4*kst + lg) ^ (sr & 7))<<4));
      }
      const char* vp = vth + t0*2 + kst*64 + lg*16;
      #pragma unroll
      for (int nt=0; nt<4; ++nt) {
        const int d = 64*w + 16*nt + l15;
        short8 vf = *(const short8*)(vp + (size_t)d*4096);
        oacc[0][nt] = __builtin_amdgcn_mfma_f32_16x16x32_bf16(wf[0], vf, oacc[0][nt], 0, 0, 0);
        oacc[1][nt] = __builtin_amdgcn_mfma_f32_16x16x32_bf16(wf[1], vf, oacc[1][nt], 0, 0, 0);
      }
    }
    __syncthreads();   // PV done before next iter overwrites W
  }

  // ---- epilogue: den reduce (lanes then waves), normalizer, LN, write ----
  #pragma unroll
  for (int mt=0; mt<2; ++mt)
    #pragma unroll
    for (int rr=0; rr<4; ++rr) {
      float v = denp[mt][rr];
      v += __shfl_xor(v, 1); v += __shfl_xor(v, 2);
      v += __shfl_xor(v, 4); v += __shfl_xor(v, 8);
      if (l15 == 0) smRed[(16*mt + 4*lg + rr)*4 + w] = v;
    }
  __syncthreads();

  float inv[2][4];
  #pragma unroll
  for (int mt=0; mt<2; ++mt)
    #pragma unroll
    for (int rr=0; rr<4; ++rr) {
      const int srel = 16*mt + 4*lg + rr;
      float dsum = smRed[srel*4+0] + smRed[srel*4+1] + smRed[srel*4+2] + smRed[srel*4+3];
      float f = flr[bhoff + s0 + srel];
      inv[mt][rr] = 1.f / (fmaxf(fabsf(dsum), f) + 1e-8f);
    }

  float s1p[2][4] = {{0,0,0,0},{0,0,0,0}}, s2p[2][4] = {{0,0,0,0},{0,0,0,0}};
  #pragma unroll
  for (int mt=0; mt<2; ++mt)
    #pragma unroll
    for (int nt=0; nt<4; ++nt)
      #pragma unroll
      for (int rr=0; rr<4; ++rr) {
        float v = oacc[mt][nt][rr] * inv[mt][rr];
        oacc[mt][nt][rr] = v;
        s1p[mt][rr] += v;
        s2p[mt][rr] += v*v;
      }
  #pragma unroll
  for (int mt=0; mt<2; ++mt)
    #pragma unroll
    for (int rr=0; rr<4; ++rr) {
      float a = s1p[mt][rr], q = s2p[mt][rr];
      a += __shfl_xor(a, 1); a += __shfl_xor(a, 2);
      a += __shfl_xor(a, 4); a += __shfl_xor(a, 8);
      q += __shfl_xor(q, 1); q += __shfl_xor(q, 2);
      q += __shfl_xor(q, 4); q += __shfl_xor(q, 8);
      if (l15 == 0) {
        const int srel = 16*mt + 4*lg + rr;
        smS1[srel*4 + w] = a;
        smS2[srel*4 + w] = q;
      }
    }
  __syncthreads();

  float g4[4];
  #pragma unroll
  for (int nt=0; nt<4; ++nt) g4[nt] = 1.f + ln_w[h*DHH + 64*w + 16*nt + l15];

  #pragma unroll
  for (int mt=0; mt<2; ++mt)
    #pragma unroll
    for (int rr=0; rr<4; ++rr) {
      const int srel = 16*mt + 4*lg + rr;
      const float ms = smS1[srel*4+0] + smS1[srel*4+1] + smS1[srel*4+2] + smS1[srel*4+3];
      const float sq = smS2[srel*4+0] + smS2[srel*4+1] + smS2[srel*4+2] + smS2[srel*4+3];
      const float mean = ms * (1.f/DHH);
      const float var  = sq * (1.f/DHH) - mean*mean;
      const float rstd = rsqrtf(var + 1e-5f);
      float* op = out + ((size_t)(b*SS + s0 + srel))*DD + h*DHH;
      #pragma unroll
      for (int nt=0; nt<4; ++nt)
        op[64*w + 16*nt + l15] = (oacc[mt][nt][rr] - mean)*rstd*g4[nt];
    }
}

// ---------------------------------------------------------------------------
extern "C" void kernel_launch(void* const* d_in, const int* in_sizes, int n_in,
                              void* d_out, int out_size, void* d_ws, size_t ws_size,
                              hipStream_t stream) {
  (void)in_sizes; (void)n_in; (void)out_size; (void)ws_size;
  const float* x    = (const float*)d_in[0];
  const float* wq   = (const float*)d_in[1];
  const float* wk   = (const float*)d_in[2];
  const float* wv   = (const float*)d_in[3];
  const float* wi   = (const float*)d_in[4];
  const float* bi   = (const float*)d_in[5];
  const float* wf   = (const float*)d_in[6];
  const float* bf   = (const float*)d_in[7];
  const float* ln_w = (const float*)d_in[8];
  float* out = (float*)d_out;
  char* ws = (char*)d_ws;

  unsigned short* QB = (unsigned short*)(ws + QB_OFF);
  unsigned short* KB = (unsigned short*)(ws + KB_OFF);
  unsigned short* VT = (unsigned short*)(ws + VT_OFF);
  unsigned short* VB = (unsigned short*)(ws + VB_OFF);
  float* IG  = (float*)(ws + IG_OFF);
  float* LSF = (float*)(ws + LSF_OFF);
  float* AA  = (float*)(ws + AA_OFF);
  float* MM  = (float*)(ws + MM_OFF);
  float* FLR = (float*)(ws + FLR_OFF);
  float* WSI = (float*)(ws + WSI_OFF);
  float* WSF = (float*)(ws + WSF_OFF);

  k_gw<<<32, 256, 0, stream>>>(wi, wf, WSI, WSF);
  k_proj<<<BB*SS, 256, 0, stream>>>(x, wq, wk, wv, WSI, bi, WSF, bf, QB, KB, VB, IG, LSF);
  k_scan<<<BHH, 256, 0, stream>>>(IG, LSF, AA, MM, FLR);
  k_vt<<<dim3(BHH, SS/64, DHH/64), 256, 0, stream>>>(VB, VT);
  k_attn<<<512, 256, 0, stream>>>(QB, KB, VT, AA, MM, FLR, ln_w, out);
}

// Round 5
// 118.911 us; speedup vs baseline: 1.0800x; 1.0800x over previous
//
#include <hip/hip_runtime.h>
#include <math.h>

// ---------------------------------------------------------------------------
// mLSTM cell, MFMA bf16. Round 5: k_attn = round-4 geometry + real pipeline:
// K reg-double-buffered (issued 1 tile ahead), V reg-staged (issued at tile
// top), W through 4KB LDS, raw s_barrier + lgkmcnt(0) only (no vmem drain ->
// prefetch stays in flight across barriers). setprio around MFMA clusters.
// No cross-wave data through global inside the loop => lgkm-only barriers are
// sufficient for correctness.
// ---------------------------------------------------------------------------

#define BB   2
#define SS   2048
#define DD   1024
#define NHH  4
#define DHH  256
#define BHH  (BB*NHH)

// Workspace byte offsets (total ~32.5 MB)
#define QB_OFF   ((size_t)0)
#define KB_OFF   ((size_t)8  << 20)
#define VT_OFF   ((size_t)16 << 20)
#define VB_OFF   ((size_t)24 << 20)
#define IG_OFF   ((size_t)32 << 20)
#define LSF_OFF  (IG_OFF  + ((size_t)64<<10))
#define AA_OFF   (LSF_OFF + ((size_t)64<<10))
#define MM_OFF   (AA_OFF  + ((size_t)64<<10))
#define FLR_OFF  (MM_OFF  + ((size_t)64<<10))
#define WSI_OFF  (FLR_OFF + ((size_t)64<<10))
#define WSF_OFF  (WSI_OFF + ((size_t)32<<10))

typedef __attribute__((ext_vector_type(8))) short short8;   // 8 bf16 (4 VGPR)
typedef __attribute__((ext_vector_type(4))) float f32x4;

__device__ __forceinline__ unsigned short f2b(float f) {
  union { float f; unsigned int u; } v; v.f = f;
  unsigned int r = (v.u + 0x7FFFu + ((v.u >> 16) & 1u)) >> 16;
  return (unsigned short)r;
}

// ---------------------------------------------------------------------------
// Kernel 0: gate weight pre-sum: wsum[n][c] = sum of 3 D-segments.
// ---------------------------------------------------------------------------
__global__ __launch_bounds__(256) void k_gw(
    const float* __restrict__ wi, const float* __restrict__ wf,
    float* __restrict__ wsi, float* __restrict__ wsf)
{
  const int idx = blockIdx.x*256 + threadIdx.x;   // 0..8191
  const int n = idx >> 10, c = idx & 1023;
  wsi[idx] = wi[n*3*DD + c] + wi[n*3*DD + DD + c] + wi[n*3*DD + 2*DD + c];
  wsf[idx] = wf[n*3*DD + c] + wf[n*3*DD + DD + c] + wf[n*3*DD + 2*DD + c];
}

// ---------------------------------------------------------------------------
// Kernel 1: headwise QKV projection (4x4 blocks) + gate GEMVs. bf16 outputs.
// ---------------------------------------------------------------------------
__global__ __launch_bounds__(256) void k_proj(
    const float* __restrict__ x,
    const float* __restrict__ wq, const float* __restrict__ wk, const float* __restrict__ wv,
    const float* __restrict__ wsi, const float* __restrict__ bi,
    const float* __restrict__ wsf, const float* __restrict__ bf,
    unsigned short* __restrict__ qb, unsigned short* __restrict__ kb,
    unsigned short* __restrict__ vb, float* __restrict__ ig, float* __restrict__ lsf)
{
  const int row = blockIdx.x;          // b*SS + s
  const int b   = row >> 11;
  const int s   = row & (SS-1);
  const int g   = threadIdx.x;         // qkv head 0..255

  const float4 xv = *(const float4*)(x + (size_t)row*DD + (g<<2));

  const int h   = g >> 6;
  const int dh0 = (g & 63) << 2;
  const size_t qi = ((size_t)(b*NHH + h)*SS + s)*DHH + dh0;

  {
    const float4 w0 = *(const float4*)(wq + g*16 + 0);
    const float4 w1 = *(const float4*)(wq + g*16 + 4);
    const float4 w2 = *(const float4*)(wq + g*16 + 8);
    const float4 w3 = *(const float4*)(wq + g*16 + 12);
    ushort4 r;
    r.x = f2b(w0.x*xv.x + w0.y*xv.y + w0.z*xv.z + w0.w*xv.w);
    r.y = f2b(w1.x*xv.x + w1.y*xv.y + w1.z*xv.z + w1.w*xv.w);
    r.z = f2b(w2.x*xv.x + w2.y*xv.y + w2.z*xv.z + w2.w*xv.w);
    r.w = f2b(w3.x*xv.x + w3.y*xv.y + w3.z*xv.z + w3.w*xv.w);
    *(ushort4*)(qb + qi) = r;
  }
  {
    const float4 w0 = *(const float4*)(wk + g*16 + 0);
    const float4 w1 = *(const float4*)(wk + g*16 + 4);
    const float4 w2 = *(const float4*)(wk + g*16 + 8);
    const float4 w3 = *(const float4*)(wk + g*16 + 12);
    ushort4 r;
    r.x = f2b(0.0625f*(w0.x*xv.x + w0.y*xv.y + w0.z*xv.z + w0.w*xv.w));
    r.y = f2b(0.0625f*(w1.x*xv.x + w1.y*xv.y + w1.z*xv.z + w1.w*xv.w));
    r.z = f2b(0.0625f*(w2.x*xv.x + w2.y*xv.y + w2.z*xv.z + w2.w*xv.w));
    r.w = f2b(0.0625f*(w3.x*xv.x + w3.y*xv.y + w3.z*xv.z + w3.w*xv.w));
    *(ushort4*)(kb + qi) = r;
  }
  {
    const float4 w0 = *(const float4*)(wv + g*16 + 0);
    const float4 w1 = *(const float4*)(wv + g*16 + 4);
    const float4 w2 = *(const float4*)(wv + g*16 + 8);
    const float4 w3 = *(const float4*)(wv + g*16 + 12);
    ushort4 r;
    r.x = f2b(w0.x*xv.x + w0.y*xv.y + w0.z*xv.z + w0.w*xv.w);
    r.y = f2b(w1.x*xv.x + w1.y*xv.y + w1.z*xv.z + w1.w*xv.w);
    r.z = f2b(w2.x*xv.x + w2.y*xv.y + w2.z*xv.z + w2.w*xv.w);
    r.w = f2b(w3.x*xv.x + w3.y*xv.y + w3.z*xv.z + w3.w*xv.w);
    *(ushort4*)(vb + qi) = r;
  }

  float pi[4], pf[4];
  const int c = g << 2;
  #pragma unroll
  for (int n=0;n<4;n++) {
    const float4 a0 = *(const float4*)(wsi + n*DD + c);
    pi[n] = a0.x*xv.x + a0.y*xv.y + a0.z*xv.z + a0.w*xv.w;
    const float4 b0 = *(const float4*)(wsf + n*DD + c);
    pf[n] = b0.x*xv.x + b0.y*xv.y + b0.z*xv.z + b0.w*xv.w;
  }
  #pragma unroll
  for (int off=32; off>0; off>>=1) {
    #pragma unroll
    for (int n=0;n<4;n++) {
      pi[n] += __shfl_down(pi[n], off);
      pf[n] += __shfl_down(pf[n], off);
    }
  }
  __shared__ float red[4][8];
  const int lane = g & 63, wid = g >> 6;
  if (lane == 0) {
    #pragma unroll
    for (int n=0;n<4;n++) { red[wid][n] = pi[n]; red[wid][4+n] = pf[n]; }
  }
  __syncthreads();
  if (g < 4) {
    const int n = g;
    float ti = red[0][n]+red[1][n]+red[2][n]+red[3][n] + bi[n];
    float tf = red[0][4+n]+red[1][4+n]+red[2][4+n]+red[3][4+n] + bf[n];
    ig[(size_t)(b*NHH+n)*SS + s] = ti;
    float ls = (tf >= 0.f) ? -log1pf(expf(-tf)) : (tf - log1pf(expf(tf)));
    lsf[(size_t)(b*NHH+n)*SS + s] = ls;
  }
}

// ---------------------------------------------------------------------------
// Kernel 2: per-(b,head) scan.
// ---------------------------------------------------------------------------
__global__ __launch_bounds__(256) void k_scan(
    const float* __restrict__ ig, const float* __restrict__ lsf,
    float* __restrict__ aa, float* __restrict__ mm, float* __restrict__ flr)
{
  const int bh = blockIdx.x;
  const int tid = threadIdx.x;
  const float* igp = ig + (size_t)bh*SS;
  const float* lsp = lsf + (size_t)bh*SS;
  float* ap = aa + (size_t)bh*SS;
  float* mp = mm + (size_t)bh*SS;
  float* fp = flr + (size_t)bh*SS;

  __shared__ float sb[256];
  const int base = tid*8;
  float l[8], c[8];
  #pragma unroll
  for (int j=0;j<8;j++) l[j] = lsp[base+j];
  c[0] = l[0];
  #pragma unroll
  for (int j=1;j<8;j++) c[j] = c[j-1] + l[j];

  sb[tid] = c[7];
  __syncthreads();
  for (int off=1; off<256; off<<=1) {
    float v = sb[tid];
    float u = (tid>=off) ? sb[tid-off] : 0.f;
    __syncthreads();
    sb[tid] = v + u;
    __syncthreads();
  }
  const float exs = (tid==0) ? 0.f : sb[tid-1];

  float cs[8], a8[8], mx[8];
  #pragma unroll
  for (int j=0;j<8;j++) { cs[j] = exs + c[j]; a8[j] = igp[base+j] - cs[j]; }
  mx[0] = a8[0];
  #pragma unroll
  for (int j=1;j<8;j++) mx[j] = fmaxf(mx[j-1], a8[j]);

  __syncthreads();
  sb[tid] = mx[7];
  __syncthreads();
  for (int off=1; off<256; off<<=1) {
    float v = sb[tid];
    float u = (tid>=off) ? sb[tid-off] : -INFINITY;
    __syncthreads();
    sb[tid] = fmaxf(v, u);
    __syncthreads();
  }
  const float exm = (tid==0) ? -INFINITY : sb[tid-1];

  #pragma unroll
  for (int j=0;j<8;j++) {
    float mmx = fmaxf(exm, mx[j]);
    ap[base+j] = a8[j];
    mp[base+j] = mmx;
    fp[base+j] = expf(-(cs[j] + mmx));
  }
}

// ---------------------------------------------------------------------------
// Kernel 3: transpose V bf16 [bh][s][d] -> Vt [bh][d][s].
// ---------------------------------------------------------------------------
__global__ __launch_bounds__(256) void k_vt(
    const unsigned short* __restrict__ vb, unsigned short* __restrict__ vt)
{
  __shared__ unsigned short tile[64][72];
  const int bh = blockIdx.x, st = blockIdx.y, dt = blockIdx.z;
  const int s0 = st*64, d0 = dt*64;
  const unsigned short* src = vb + ((size_t)bh*SS + s0)*DHH + d0;
  #pragma unroll
  for (int j=0;j<2;j++){
    int f = threadIdx.x + j*256;           // 0..511
    int r = f>>3, c = (f&7)*8;
    *(uint4*)&tile[r][c] = *(const uint4*)(src + (size_t)r*DHH + c);
  }
  __syncthreads();
  unsigned short* dst = vt + ((size_t)bh*DHH + d0)*SS + s0;
  #pragma unroll
  for (int j=0;j<2;j++){
    int f = threadIdx.x + j*256;
    int dr = f>>3, sc = (f&7)*8;
    unsigned short tmp[8];
    #pragma unroll
    for (int i=0;i<8;i++) tmp[i] = tile[sc+i][dr];
    *(uint4*)(dst + (size_t)dr*SS + sc) = *(uint4*)tmp;
  }
}

// ---------------------------------------------------------------------------
// Kernel 4: MFMA attention, software-pipelined.
// 512 blocks = 8 bh (XCD pin via bid&7) x 64 q-tiles of 32 rows, depth-paired
// (j, j+32 -> 33 tiles per CU). 4 waves; wave w owns QKT cols [16w,16w+16)
// and PV d-slice [64w,64w+64). Q register-resident. K double-buffered in
// regs (issued one tile ahead), V reg-staged at tile top. W via 4KB swizzled
// LDS. Raw s_barrier + lgkmcnt(0) only -> global prefetch survives barriers.
// ---------------------------------------------------------------------------
__global__ __launch_bounds__(256, 2) void k_attn(
    const unsigned short* __restrict__ qb, const unsigned short* __restrict__ kb,
    const unsigned short* __restrict__ vt,
    const float* __restrict__ ab, const float* __restrict__ mb,
    const float* __restrict__ flr, const float* __restrict__ ln_w,
    float* __restrict__ out)
{
  __shared__ __align__(16) char smWb[32*128];   // W: 32 rows x 128B, swizzled
  __shared__ float smRed[32*4];
  __shared__ float smS1[32*4];
  __shared__ float smS2[32*4];

  const int bid = blockIdx.x;
  const int bh  = bid & 7;                 // XCD pin
  const int j   = bid >> 3;                // 0..63
  const int rt  = (j < 32) ? (2*j) : (127 - 2*j);
  const int s0  = rt * 32;
  const int nkt = (32*rt + 95) >> 6;       // ceil((s0+32)/64), 1..32

  const int tid  = threadIdx.x;
  const int lane = tid & 63;
  const int w    = tid >> 6;               // wave 0..3
  const int l15  = lane & 15, lg = lane >> 4;
  const int bhoff = bh * SS;
  const int b = bh >> 2, h = bh & 3;

  const char* kbh = (const char*)(kb + (size_t)bh*SS*DHH);   // rows of 512B
  const char* vth = (const char*)(vt + (size_t)bh*DHH*SS);   // d-rows of 4096B

  // Q register-resident: 32 rows (mt bands of 16)
  short8 qf[2][8];
  {
    const unsigned short* qp = qb + ((size_t)bh*SS + s0)*DHH;
    #pragma unroll
    for (int mt=0; mt<2; ++mt)
      #pragma unroll
      for (int ks=0; ks<8; ++ks)
        qf[mt][ks] = *(const short8*)(qp + (16*mt + l15)*DHH + 32*ks + 8*lg);
  }
  float mrow[2][4];
  #pragma unroll
  for (int mt=0; mt<2; ++mt)
    #pragma unroll
    for (int rr=0; rr<4; ++rr)
      mrow[mt][rr] = mb[bhoff + s0 + 16*mt + 4*lg + rr];

  f32x4 oacc[2][4];
  #pragma unroll
  for (int mt=0; mt<2; ++mt)
    #pragma unroll
    for (int nt=0; nt<4; ++nt)
      oacc[mt][nt] = (f32x4){0.f,0.f,0.f,0.f};
  float denp[2][4] = {{0.f,0.f,0.f,0.f},{0.f,0.f,0.f,0.f}};

  const int trel = 16*w + l15;             // QKT col within k-tile, 0..63

  short8 kA[8], kB[8], vR[8];

  // prologue: issue K(0) into kA
  {
    const char* kp = kbh + (size_t)trel*512 + lg*16;
    #pragma unroll
    for (int ks=0; ks<8; ++ks) kA[ks] = *(const short8*)(kp + ks*64);
  }

#define TILE_BODY(KC, KN)                                                      \
  do {                                                                         \
    const int t0 = kt*64;                                                      \
    /* V(kt) issue (consumed after QK+W) */                                    \
    {                                                                          \
      const char* vp = vth + (size_t)t0*2 + lg*16;                             \
      _Pragma("unroll")                                                        \
      for (int i=0;i<8;++i) {                                                  \
        const int kst = i>>2, nt = i&3;                                        \
        const int d = 64*w + 16*nt + l15;                                      \
        vR[i] = *(const short8*)(vp + (size_t)d*4096 + kst*64);                \
      }                                                                        \
    }                                                                          \
    const float av = ab[bhoff + t0 + trel];                                    \
    /* QK from KC (issued one tile ago) */                                     \
    f32x4 sA = (f32x4){0.f,0.f,0.f,0.f};                                       \
    f32x4 sB = (f32x4){0.f,0.f,0.f,0.f};                                       \
    __builtin_amdgcn_s_setprio(1);                                             \
    _Pragma("unroll")                                                          \
    for (int ks=0; ks<8; ++ks) {                                               \
      sA = __builtin_amdgcn_mfma_f32_16x16x32_bf16(qf[0][ks], KC[ks], sA, 0,0,0); \
      sB = __builtin_amdgcn_mfma_f32_16x16x32_bf16(qf[1][ks], KC[ks], sB, 0,0,0); \
    }                                                                          \
    __builtin_amdgcn_s_setprio(0);                                             \
    /* issue K(kt+1) into KN */                                                \
    if (kt+1 < nkt) {                                                          \
      const char* kp = kbh + (size_t)(t0 + 64 + trel)*512 + lg*16;             \
      _Pragma("unroll")                                                        \
      for (int ks=0; ks<8; ++ks) KN[ks] = *(const short8*)(kp + ks*64);        \
    }                                                                          \
    /* W = mask * qk * exp(a[t]-m[s]) -> bf16 swizzled LDS */                  \
    {                                                                          \
      const bool lastt = (kt == nkt-1);                                        \
      _Pragma("unroll")                                                        \
      for (int mt=0; mt<2; ++mt) {                                             \
        _Pragma("unroll")                                                      \
        for (int rr=0; rr<4; ++rr) {                                           \
          const int srel = 16*mt + 4*lg + rr;                                  \
          float wv = (mt ? sB[rr] : sA[rr]) * __expf(av - mrow[mt][rr]);       \
          if (lastt && (t0 + trel > s0 + srel)) wv = 0.f;                      \
          denp[mt][rr] += wv;                                                  \
          *(unsigned short*)(smWb + (size_t)srel*128 +                         \
              (((trel >> 3) ^ (srel & 7))<<4) + ((trel & 7)<<1)) = f2b(wv);    \
        }                                                                      \
      }                                                                        \
    }                                                                          \
    asm volatile("s_waitcnt lgkmcnt(0)" ::: "memory");                         \
    __builtin_amdgcn_s_barrier();                                              \
    asm volatile("" ::: "memory");                                             \
    /* PV: oacc += W @ V */                                                    \
    _Pragma("unroll")                                                          \
    for (int kst=0; kst<2; ++kst) {                                            \
      short8 wf0, wf1;                                                         \
      { const int sr = l15;                                                    \
        wf0 = *(const short8*)(smWb + (size_t)sr*128 + (((4*kst+lg)^(sr&7))<<4)); } \
      { const int sr = 16 + l15;                                               \
        wf1 = *(const short8*)(smWb + (size_t)sr*128 + (((4*kst+lg)^(sr&7))<<4)); } \
      __builtin_amdgcn_s_setprio(1);                                           \
      _Pragma("unroll")                                                        \
      for (int nt=0; nt<4; ++nt) {                                             \
        oacc[0][nt] = __builtin_amdgcn_mfma_f32_16x16x32_bf16(wf0, vR[kst*4+nt], oacc[0][nt], 0,0,0); \
        oacc[1][nt] = __builtin_amdgcn_mfma_f32_16x16x32_bf16(wf1, vR[kst*4+nt], oacc[1][nt], 0,0,0); \
      }                                                                        \
      __builtin_amdgcn_s_setprio(0);                                           \
    }                                                                          \
    asm volatile("s_waitcnt lgkmcnt(0)" ::: "memory");                         \
    __builtin_amdgcn_s_barrier();                                              \
    asm volatile("" ::: "memory");                                             \
  } while(0)

  {
    int kt = 0;
    while (kt < nkt) {
      TILE_BODY(kA, kB);
      ++kt;
      if (kt >= nkt) break;
      TILE_BODY(kB, kA);
      ++kt;
    }
  }
#undef TILE_BODY

  // ---- epilogue: den reduce (lanes then waves), normalizer, LN, write ----
  #pragma unroll
  for (int mt=0; mt<2; ++mt)
    #pragma unroll
    for (int rr=0; rr<4; ++rr) {
      float v = denp[mt][rr];
      v += __shfl_xor(v, 1); v += __shfl_xor(v, 2);
      v += __shfl_xor(v, 4); v += __shfl_xor(v, 8);
      if (l15 == 0) smRed[(16*mt + 4*lg + rr)*4 + w] = v;
    }
  __syncthreads();

  float inv[2][4];
  #pragma unroll
  for (int mt=0; mt<2; ++mt)
    #pragma unroll
    for (int rr=0; rr<4; ++rr) {
      const int srel = 16*mt + 4*lg + rr;
      float dsum = smRed[srel*4+0] + smRed[srel*4+1] + smRed[srel*4+2] + smRed[srel*4+3];
      float f = flr[bhoff + s0 + srel];
      inv[mt][rr] = 1.f / (fmaxf(fabsf(dsum), f) + 1e-8f);
    }

  float s1p[2][4] = {{0,0,0,0},{0,0,0,0}}, s2p[2][4] = {{0,0,0,0},{0,0,0,0}};
  #pragma unroll
  for (int mt=0; mt<2; ++mt)
    #pragma unroll
    for (int nt=0; nt<4; ++nt)
      #pragma unroll
      for (int rr=0; rr<4; ++rr) {
        float v = oacc[mt][nt][rr] * inv[mt][rr];
        oacc[mt][nt][rr] = v;
        s1p[mt][rr] += v;
        s2p[mt][rr] += v*v;
      }
  #pragma unroll
  for (int mt=0; mt<2; ++mt)
    #pragma unroll
    for (int rr=0; rr<4; ++rr) {
      float a = s1p[mt][rr], q = s2p[mt][rr];
      a += __shfl_xor(a, 1); a += __shfl_xor(a, 2);
      a += __shfl_xor(a, 4); a += __shfl_xor(a, 8);
      q += __shfl_xor(q, 1); q += __shfl_xor(q, 2);
      q += __shfl_xor(q, 4); q += __shfl_xor(q, 8);
      if (l15 == 0) {
        const int srel = 16*mt + 4*lg + rr;
        smS1[srel*4 + w] = a;
        smS2[srel*4 + w] = q;
      }
    }
  __syncthreads();

  float g4[4];
  #pragma unroll
  for (int nt=0; nt<4; ++nt) g4[nt] = 1.f + ln_w[h*DHH + 64*w + 16*nt + l15];

  #pragma unroll
  for (int mt=0; mt<2; ++mt)
    #pragma unroll
    for (int rr=0; rr<4; ++rr) {
      const int srel = 16*mt + 4*lg + rr;
      const float ms = smS1[srel*4+0] + smS1[srel*4+1] + smS1[srel*4+2] + smS1[srel*4+3];
      const float sq = smS2[srel*4+0] + smS2[srel*4+1] + smS2[srel*4+2] + smS2[srel*4+3];
      const float mean = ms * (1.f/DHH);
      const float var  = sq * (1.f/DHH) - mean*mean;
      const float rstd = rsqrtf(var + 1e-5f);
      float* op = out + ((size_t)(b*SS + s0 + srel))*DD + h*DHH;
      #pragma unroll
      for (int nt=0; nt<4; ++nt)
        op[64*w + 16*nt + l15] = (oacc[mt][nt][rr] - mean)*rstd*g4[nt];
    }
}

// ---------------------------------------------------------------------------
extern "C" void kernel_launch(void* const* d_in, const int* in_sizes, int n_in,
                              void* d_out, int out_size, void* d_ws, size_t ws_size,
                              hipStream_t stream) {
  (void)in_sizes; (void)n_in; (void)out_size; (void)ws_size;
  const float* x    = (const float*)d_in[0];
  const float* wq   = (const float*)d_in[1];
  const float* wk   = (const float*)d_in[2];
  const float* wv   = (const float*)d_in[3];
  const float* wi   = (const float*)d_in[4];
  const float* bi   = (const float*)d_in[5];
  const float* wf   = (const float*)d_in[6];
  const float* bf   = (const float*)d_in[7];
  const float* ln_w = (const float*)d_in[8];
  float* out = (float*)d_out;
  char* ws = (char*)d_ws;

  unsigned short* QB = (unsigned short*)(ws + QB_OFF);
  unsigned short* KB = (unsigned short*)(ws + KB_OFF);
  unsigned short* VT = (unsigned short*)(ws + VT_OFF);
  unsigned short* VB = (unsigned short*)(ws + VB_OFF);
  float* IG  = (float*)(ws + IG_OFF);
  float* LSF = (float*)(ws + LSF_OFF);
  float* AA  = (float*)(ws + AA_OFF);
  float* MM  = (float*)(ws + MM_OFF);
  float* FLR = (float*)(ws + FLR_OFF);
  float* WSI = (float*)(ws + WSI_OFF);
  float* WSF = (float*)(ws + WSF_OFF);

  k_gw<<<32, 256, 0, stream>>>(wi, wf, WSI, WSF);
  k_proj<<<BB*SS, 256, 0, stream>>>(x, wq, wk, wv, WSI, bi, WSF, bf, QB, KB, VB, IG, LSF);
  k_scan<<<BHH, 256, 0, stream>>>(IG, LSF, AA, MM, FLR);
  k_vt<<<dim3(BHH, SS/64, DHH/64), 256, 0, stream>>>(VB, VT);
  k_attn<<<512, 256, 0, stream>>>(QB, KB, VT, AA, MM, FLR, ln_w, out);
}